// Round 1
// 415.708 us; speedup vs baseline: 1.0834x; 1.0834x over previous
//
#include <hip/hip_runtime.h>
#include <hip/hip_bf16.h>
#include <math.h>

#define BATCH 4
#define SEQ   2048
#define DMODEL 1024

typedef __attribute__((ext_vector_type(8))) short bf16x8;
typedef __attribute__((ext_vector_type(4))) float floatx4;

// async 16B/lane global->LDS. lds pointer MUST be wave-uniform; dest = base + lane*16.
__device__ __forceinline__ void async_copy16(const void* g, void* lds) {
    __builtin_amdgcn_global_load_lds(
        reinterpret_cast<const unsigned int __attribute__((address_space(1)))*>(
            reinterpret_cast<unsigned long long>(g)),
        reinterpret_cast<unsigned int __attribute__((address_space(3)))*>(
            (unsigned int)reinterpret_cast<unsigned long long>(lds)),
        16, 0, 0);
}

#define VMCNT(n) asm volatile("s_waitcnt vmcnt(" #n ")" ::: "memory")
#define SCHED_FENCE() __builtin_amdgcn_sched_barrier(0)

// ============================================================================
// 8-phase-style 256-row GEMM (T1+T2+T3+T4+T5 port of the m201 template).
// C = (A @ B_storage^T + bias) * scale, A:[M,K] bf16 row-major (optionally
// K-concat split across A0/A1, each [M, K/2]), B_storage:[N,Kb] bf16 with
// K-index wrap (Kb <= K, pow2). 512 threads = 8 waves (2M x 4N), BM=256,
// BK=32, 4-slot LDS ring, counted vmcnt (never 0 in steady state), raw
// s_barrier (no vmcnt-draining __syncthreads in the loop), XOR chunk-swizzle
// on LDS (pre-swizzled global source + swizzled ds_read: rule 21).
// BN=256: 2 phases/tile, 16 MFMA each. BN=128: 1 phase/tile, 16 MFMA.
// ============================================================================
template<bool ASPLIT, int BN, bool HAS_BIAS, bool OUT_TRANS>
__global__ __launch_bounds__(512, 1)
void gemm8p(const __hip_bfloat16* __restrict__ A0, const __hip_bfloat16* __restrict__ A1,
            const __hip_bfloat16* __restrict__ B, const float* __restrict__ bias,
            float* __restrict__ C, int M, int N, int K, int Kb, float scale,
            long sAb, long sBb, long sCb)
{
    constexpr int BM = 256, BK = 32;
    constexpr int WN   = BN / 4;            // wave N-width: 64 or 32
    constexpr int NF   = WN / 16;           // B frags/wave: 4 or 2
    constexpr int NPH  = (NF == 4) ? 2 : 1; // phases per K-tile
    constexpr int MSUB = 8 / NPH;           // A frags per phase: 4 or 8
    constexpr int CB   = BN / 128;          // B stage calls/tile: 2 or 1
    constexpr int CALLS = 2 + CB;           // loads/wave/tile: 4 or 3

    __shared__ __align__(16) __hip_bfloat16 sA[4][BM * BK];
    __shared__ __align__(16) __hip_bfloat16 sB[4][BN * BK];

    const int bz = blockIdx.z;
    A0 += (long)bz * sAb;
    if (ASPLIT) A1 += (long)bz * sAb;
    B += (long)bz * sBb;
    C += (long)bz * sCb;

    // T1: XCD-bijective block swizzle (nwg per z slice is a multiple of 8 here)
    int b = blockIdx.y * gridDim.x + blockIdx.x;
    const int nwg = gridDim.x * gridDim.y;
    const int cpx = nwg >> 3;
    b = (b & 7) * cpx + (b >> 3);
    const int col0 = (b % gridDim.x) * BN;
    const int row0 = (b / gridDim.x) * BM;

    const int tid  = threadIdx.x;
    const int wave = tid >> 6, lane = tid & 63;
    const int wm = wave >> 2, wn = wave & 3;   // 2 x 4 wave grid
    const int fr = lane & 15, fq = lane >> 4;  // fragment row / k-quad

    const int NT  = K / BK;
    const int KA  = ASPLIT ? (K >> 1) : K;     // per-source A row stride
    const int kbm = Kb - 1;

    // staging geometry: one call = 128 rows x 32 cols (8 KB) = 512 thr x 16 B
    const int s_r  = (wave << 4) + (lane >> 2); // row within call [0,128)
    const int s_c4 = lane & 3;                  // physical 16B chunk

    auto stageA = [&](int t, int c) {
        const int lr = (c << 7) + s_r;                       // tile row
        const int ch = (s_c4 ^ ((lr >> 1) & 3)) << 3;        // pre-swizzled src chunk
        int k0 = t << 5;
        const __hip_bfloat16* src = A0;
        if (ASPLIT && k0 >= KA) { src = A1; k0 -= KA; }
        async_copy16(src + (long)(row0 + lr) * KA + k0 + ch,
                     &sA[t & 3][((c << 7) + (wave << 4)) * BK]);
    };
    auto stageB = [&](int t, int c) {
        const int lr = (c << 7) + s_r;
        const int ch = (s_c4 ^ ((lr >> 1) & 3)) << 3;
        const int k0 = (t << 5) & kbm;                       // K-wrap for concat trick
        async_copy16(B + (long)(col0 + lr) * Kb + k0 + ch,
                     &sB[t & 3][((c << 7) + (wave << 4)) * BK]);
    };
    auto readA = [&](int slot, int i) -> bf16x8 {
        const int lr = (wm << 7) + (i << 4) + fr;
        return *(const bf16x8*)&sA[slot][lr * BK + ((fq ^ ((lr >> 1) & 3)) << 3)];
    };
    auto readB = [&](int slot, int j) -> bf16x8 {
        const int lr = wn * WN + (j << 4) + fr;
        return *(const bf16x8*)&sB[slot][lr * BK + ((fq ^ ((lr >> 1) & 3)) << 3)];
    };

    floatx4 acc[8][NF];
    #pragma unroll
    for (int i = 0; i < 8; ++i)
        #pragma unroll
        for (int j = 0; j < NF; ++j) acc[i][j] = (floatx4){0.f, 0.f, 0.f, 0.f};

    // prologue: stage tiles 0,1,2 (ring slots 0..2); wait so tile 0 is resident
    #pragma unroll
    for (int t = 0; t < 3; ++t) {
        stageA(t, 0); stageA(t, 1);
        stageB(t, 0); if (CB == 2) stageB(t, 1);
    }
    if constexpr (CALLS == 4) { VMCNT(8); } else { VMCNT(6); }
    __builtin_amdgcn_s_barrier();

    bf16x8 bReg[NF], aReg[MSUB];

    for (int t = 0; t < NT; ++t) {
        const int slot = t & 3;
        const bool pf = (t + 3) < NT;   // prefetch tile t+3 into slot (t+3)&3

        // ---- phase 0: ds_reads + A-stage (and B-stage when single-phase)
        #pragma unroll
        for (int j = 0; j < NF; ++j) bReg[j] = readB(slot, j);
        #pragma unroll
        for (int i = 0; i < MSUB; ++i) aReg[i] = readA(slot, i);
        if (pf) {
            stageA(t + 3, 0); stageA(t + 3, 1);
            if (NPH == 1) { stageB(t + 3, 0); if (CB == 2) stageB(t + 3, 1); }
        }
        SCHED_FENCE();
        __builtin_amdgcn_s_barrier();
        __builtin_amdgcn_s_setprio(1);
        #pragma unroll
        for (int i = 0; i < MSUB; ++i)
            #pragma unroll
            for (int j = 0; j < NF; ++j)
                acc[i][j] = __builtin_amdgcn_mfma_f32_16x16x32_bf16(aReg[i], bReg[j], acc[i][j], 0, 0, 0);
        __builtin_amdgcn_s_setprio(0);
        SCHED_FENCE();

        if constexpr (NPH == 2) {
            __builtin_amdgcn_s_barrier();
            // ---- phase 1: remaining A frags + B-stage; B frags reused from regs
            #pragma unroll
            for (int i = 0; i < MSUB; ++i) aReg[i] = readA(slot, MSUB + i);
            if (pf) { stageB(t + 3, 0); stageB(t + 3, 1); }
            SCHED_FENCE();
            __builtin_amdgcn_s_barrier();
            __builtin_amdgcn_s_setprio(1);
            #pragma unroll
            for (int i = 0; i < MSUB; ++i)
                #pragma unroll
                for (int j = 0; j < NF; ++j)
                    acc[MSUB + i][j] = __builtin_amdgcn_mfma_f32_16x16x32_bf16(aReg[i], bReg[j], acc[MSUB + i][j], 0, 0, 0);
            __builtin_amdgcn_s_setprio(0);
            SCHED_FENCE();
        }

        // ---- tile boundary: counted vmcnt (tiles t+2,t+3 may stay in flight)
        if (t + 1 < NT) {
            const int ahead = (t + 3 < NT) ? 2 : ((t + 2 < NT) ? 1 : 0);
            if (ahead == 2)      { if constexpr (CALLS == 4) { VMCNT(8); } else { VMCNT(6); } }
            else if (ahead == 1) { if constexpr (CALLS == 4) { VMCNT(4); } else { VMCNT(3); } }
            else                 { VMCNT(0); }
            __builtin_amdgcn_s_barrier();
        }
    }

    // epilogue — C/D layout: col = lane&15, row = (lane>>4)*4 + reg
    #pragma unroll
    for (int i = 0; i < 8; ++i) {
        #pragma unroll
        for (int r = 0; r < 4; ++r) {
            const int row = row0 + (wm << 7) + (i << 4) + (fq << 2) + r;
            #pragma unroll
            for (int j = 0; j < NF; ++j) {
                const int col = col0 + wn * WN + (j << 4) + fr;
                float val = acc[i][j][r];
                if (HAS_BIAS) val += bias[(long)row * N + col];
                val *= scale;
                if (OUT_TRANS) C[(long)col * M + row] = val;
                else           C[(long)row * N + col] = val;
            }
        }
    }
}

// ============================================================================
// legacy 128^2 GEMM (kept for qpe/kpe and biasM: small-K shapes, 256-wg grids)
// ============================================================================
template<bool SPLIT_A, bool HAS_BIAS, bool OUT_TRANS, bool OUT_BF16>
__global__ __launch_bounds__(256, 1)
void mfma_gemm(const __hip_bfloat16* __restrict__ Ah, const __hip_bfloat16* __restrict__ Al,
               const __hip_bfloat16* __restrict__ Bh,
               const float* __restrict__ bias, void* __restrict__ Cvoid,
               int M, int N, int K, float scale,
               long sAb, long sBb, long sCb)
{
    constexpr int NA = SPLIT_A ? 2 : 1;
    __shared__ __align__(16) __hip_bfloat16 sA[NA][128 * 32];
    __shared__ __align__(16) __hip_bfloat16 sB[128 * 32];

    const int bz = blockIdx.z;
    Ah += (long)bz * sAb;
    Bh += (long)bz * sBb;
    if (SPLIT_A) Al += (long)bz * sAb;

    const int row0 = blockIdx.y * 128;
    const int col0 = blockIdx.x * 128;
    const int tid  = threadIdx.x;
    const int wave = tid >> 6;
    const int lane = tid & 63;

    const int srow   = wave * 16 + (lane >> 2);
    const int schunk = (lane & 3) * 8;

    const int wm = (wave >> 1) * 64;
    const int wn = (wave & 1) * 64;
    const int fr = lane & 15;
    const int fk = (lane >> 4) * 8;

    const floatx4 zero = {0.f, 0.f, 0.f, 0.f};
    floatx4 acc[4][4];
    #pragma unroll
    for (int i = 0; i < 4; ++i)
        #pragma unroll
        for (int j = 0; j < 4; ++j) acc[i][j] = zero;

    for (int k0 = 0; k0 < K; k0 += 32) {
        #pragma unroll
        for (int t = 0; t < 2; ++t) {
            const long arow = (long)(row0 + t * 64 + srow);
            const long brow = (long)(col0 + t * 64 + srow);
            const int  soff = (t * 64 + wave * 16) * 32;
            async_copy16(Ah + arow * K + k0 + schunk, &sA[0][soff]);
            async_copy16(Bh + brow * K + k0 + schunk, &sB[soff]);
            if (SPLIT_A)
                async_copy16(Al + arow * K + k0 + schunk, &sA[NA - 1][soff]);
        }
        __syncthreads();

        bf16x8 aH[4], bH[4];
        #pragma unroll
        for (int i = 0; i < 4; ++i) aH[i] = *(const bf16x8*)&sA[0][(wm + i * 16 + fr) * 32 + fk];
        #pragma unroll
        for (int j = 0; j < 4; ++j) bH[j] = *(const bf16x8*)&sB[(wn + j * 16 + fr) * 32 + fk];

        if (SPLIT_A) {
            bf16x8 aL[4];
            #pragma unroll
            for (int i = 0; i < 4; ++i) aL[i] = *(const bf16x8*)&sA[NA - 1][(wm + i * 16 + fr) * 32 + fk];
            #pragma unroll
            for (int i = 0; i < 4; ++i)
                #pragma unroll
                for (int j = 0; j < 4; ++j) {
                    acc[i][j] = __builtin_amdgcn_mfma_f32_16x16x32_bf16(aH[i], bH[j], acc[i][j], 0, 0, 0);
                    acc[i][j] = __builtin_amdgcn_mfma_f32_16x16x32_bf16(aL[i], bH[j], acc[i][j], 0, 0, 0);
                }
        } else {
            #pragma unroll
            for (int i = 0; i < 4; ++i)
                #pragma unroll
                for (int j = 0; j < 4; ++j)
                    acc[i][j] = __builtin_amdgcn_mfma_f32_16x16x32_bf16(aH[i], bH[j], acc[i][j], 0, 0, 0);
        }
        __syncthreads();
    }

    float* Cf = (float*)Cvoid + (long)bz * sCb;
    __hip_bfloat16* Cb = (__hip_bfloat16*)Cvoid + (long)bz * sCb;
    #pragma unroll
    for (int i = 0; i < 4; ++i) {
        #pragma unroll
        for (int r = 0; r < 4; ++r) {
            const int row = row0 + wm + i * 16 + (lane >> 4) * 4 + r;
            #pragma unroll
            for (int j = 0; j < 4; ++j) {
                const int col = col0 + wn + j * 16 + (lane & 15);
                float val = acc[i][j][r];
                if (HAS_BIAS) val += bias[(long)row * N + col];
                val *= scale;
                if (OUT_BF16)       Cb[(long)row * N + col] = __float2bfloat16(val);
                else if (OUT_TRANS) Cf[(long)col * M + row] = val;
                else                Cf[(long)row * N + col] = val;
            }
        }
    }
}

// fp32 -> bf16, 4 elems/thread
__global__ __launch_bounds__(256)
void convert_bf16_kernel(const float* __restrict__ in, __hip_bfloat16* __restrict__ out, long n)
{
    const long i = ((long)blockIdx.x * 256 + threadIdx.x) * 4;
    if (i >= n) return;
    float va[4];
    *(float4*)va = *(const float4*)(in + i);
    __align__(8) __hip_bfloat16 h[4];
    #pragma unroll
    for (int j = 0; j < 4; ++j) h[j] = __float2bfloat16(va[j]);
    *(uint2*)(out + i) = *(uint2*)h;
}

// fp32 -> (hi, lo) bf16 pair: hi = bf16(x), lo = bf16(x - float(hi))
__global__ __launch_bounds__(256)
void split_convert_kernel(const float* __restrict__ in, __hip_bfloat16* __restrict__ hi,
                          __hip_bfloat16* __restrict__ lo, long n)
{
    const long i = ((long)blockIdx.x * 256 + threadIdx.x) * 4;
    if (i >= n) return;
    float va[4];
    *(float4*)va = *(const float4*)(in + i);
    __align__(8) __hip_bfloat16 h[4], l[4];
    #pragma unroll
    for (int j = 0; j < 4; ++j) {
        h[j] = __float2bfloat16(va[j]);
        l[j] = __float2bfloat16(va[j] - __bfloat162float(h[j]));
    }
    *(uint2*)(hi + i) = *(uint2*)h;
    *(uint2*)(lo + i) = *(uint2*)l;
}

// in [R][C] fp32 -> out [C][R] bf16 (batched via blockIdx.z)
__global__ __launch_bounds__(256)
void transpose_convert_kernel(const float* __restrict__ in, __hip_bfloat16* __restrict__ out,
                              int R, int C, long sIn, long sOut)
{
    in  += (long)blockIdx.z * sIn;
    out += (long)blockIdx.z * sOut;
    __shared__ float t[32][33];
    const int c0 = blockIdx.x * 32, r0 = blockIdx.y * 32;
    for (int i = threadIdx.y; i < 32; i += 8)
        t[i][threadIdx.x] = in[(long)(r0 + i) * C + c0 + threadIdx.x];
    __syncthreads();
    for (int i = threadIdx.y; i < 32; i += 8)
        out[(long)(c0 + i) * R + r0 + threadIdx.x] = __float2bfloat16(t[threadIdx.x][i]);
}

// in-place row softmax over rows of length SEQ; also emits bf16 copy.
__global__ __launch_bounds__(256)
void softmax_kernel(float* __restrict__ data, __hip_bfloat16* __restrict__ data_bf)
{
    const long row = blockIdx.x;
    float* p = data + row * (long)SEQ;
    __hip_bfloat16* pb = data_bf + row * (long)SEQ;
    const int tid = threadIdx.x;
    const int PER = SEQ / 256;  // 8

    float v[PER];
    float m = -1e30f;
    #pragma unroll
    for (int i = 0; i < PER; ++i) {
        v[i] = p[tid + i * 256];
        m = fmaxf(m, v[i]);
    }
    __shared__ float red[256];
    red[tid] = m;
    __syncthreads();
    #pragma unroll
    for (int s = 128; s > 0; s >>= 1) {
        if (tid < s) red[tid] = fmaxf(red[tid], red[tid + s]);
        __syncthreads();
    }
    m = red[0];
    __syncthreads();
    float sum = 0.f;
    #pragma unroll
    for (int i = 0; i < PER; ++i) {
        v[i] = __expf(v[i] - m);
        sum += v[i];
    }
    red[tid] = sum;
    __syncthreads();
    #pragma unroll
    for (int s = 128; s > 0; s >>= 1) {
        if (tid < s) red[tid] += red[tid + s];
        __syncthreads();
    }
    const float inv = 1.0f / red[0];
    #pragma unroll
    for (int i = 0; i < PER; ++i) {
        const float a = v[i] * inv;
        p[tid + i * 256]  = a;
        pb[tid + i * 256] = __float2bfloat16(a);
    }
}

extern "C" void kernel_launch(void* const* d_in, const int* in_sizes, int n_in,
                              void* d_out, int out_size, void* d_ws, size_t ws_size,
                              hipStream_t stream)
{
    const float* q  = (const float*)d_in[0];   // [4, 2048, 1024]
    const float* k  = (const float*)d_in[1];
    const float* v  = (const float*)d_in[2];
    const float* pe = (const float*)d_in[3];   // [10000, 1024], first 2048 rows used
    const float* Uq = (const float*)d_in[4];   // [1024, 1024] (x @ Uq)
    const float* Uk = (const float*)d_in[5];

    float* out      = (float*)d_out;
    float* ctx_out  = out;                                   // [4][1024][2048] (context^T per batch)
    float* attn_out = out + (long)BATCH * SEQ * DMODEL;      // [4][2048][2048]

    const long SD = (long)BATCH * SEQ * DMODEL;   // 8.4M elems
    char* w = (char*)d_ws;
    __hip_bfloat16* q_hi  = (__hip_bfloat16*)w;  w += SD * 2;
    __hip_bfloat16* q_lo  = (__hip_bfloat16*)w;  w += SD * 2;
    __hip_bfloat16* k_bf  = (__hip_bfloat16*)w;  w += SD * 2;
    __hip_bfloat16* pe_bf = (__hip_bfloat16*)w;  w += (long)SEQ * DMODEL * 2;
    __hip_bfloat16* UqT   = (__hip_bfloat16*)w;  w += (long)DMODEL * DMODEL * 2;  // UqT/UkT contiguous
    __hip_bfloat16* UkT   = (__hip_bfloat16*)w;  w += (long)DMODEL * DMODEL * 2;
    __hip_bfloat16* qpe_bf= (__hip_bfloat16*)w;  w += (long)SEQ * DMODEL * 2;     // qpe/kpe contiguous
    __hip_bfloat16* kpe_bf= (__hip_bfloat16*)w;  w += (long)SEQ * DMODEL * 2;
    float*          biasM = (float*)w;           w += (long)SEQ * SEQ * 4;
    // aliases (lifetimes disjoint, stream-ordered):
    __hip_bfloat16* attn_bf = q_hi;   // 33.5M elems needed = q_hi+q_lo region; written by softmax
    __hip_bfloat16* vT      = k_bf;   // 8.4M elems = k_bf region; written after scores GEMM

    const float inv_scale = 1.0f / sqrtf(128.0f);

    // --- conversions
    convert_bf16_kernel<<<dim3((SEQ * DMODEL) / 4 / 256), 256, 0, stream>>>(pe, pe_bf, (long)SEQ * DMODEL);
    transpose_convert_kernel<<<dim3(DMODEL / 32, DMODEL / 32, 1), dim3(32, 8), 0, stream>>>(
        Uq, UqT, DMODEL, DMODEL, 0, 0);
    transpose_convert_kernel<<<dim3(DMODEL / 32, DMODEL / 32, 1), dim3(32, 8), 0, stream>>>(
        Uk, UkT, DMODEL, DMODEL, 0, 0);
    split_convert_kernel<<<dim3(SD / 4 / 256), 256, 0, stream>>>(q, q_hi, q_lo, SD);
    convert_bf16_kernel<<<dim3(SD / 4 / 256), 256, 0, stream>>>(k, k_bf, SD);

    // --- qpe = pe @ Uq, kpe = pe @ Uk  (one batched launch, bf16 out; legacy kernel)
    mfma_gemm<false, false, false, true><<<dim3(DMODEL / 128, SEQ / 128, 2), 256, 0, stream>>>(
        pe_bf, nullptr, UqT, nullptr, qpe_bf, SEQ, DMODEL, DMODEL, 1.0f,
        0, (long)DMODEL * DMODEL, (long)SEQ * DMODEL);

    // --- biasM = qpe @ kpe^T (fp32; legacy kernel)
    mfma_gemm<false, false, false, false><<<dim3(SEQ / 128, SEQ / 128, 1), 256, 0, stream>>>(
        qpe_bf, nullptr, kpe_bf, nullptr, biasM, SEQ, SEQ, DMODEL, 1.0f, 0, 0, 0);

    // --- scores = ((q_hi+q_lo) @ k^T + biasM) * inv_scale
    //     8-phase 256x256, split via K-concat: A = [q_hi | q_lo] (K=2048),
    //     B = k wrapped twice (Kb=1024). Batched z=4, 64 wgs/z -> 256 wgs.
    gemm8p<true, 256, true, false><<<dim3(SEQ / 256, SEQ / 256, BATCH), 512, 0, stream>>>(
        q_hi, q_lo, k_bf, biasM, attn_out, SEQ, SEQ, 2 * DMODEL, DMODEL, inv_scale,
        (long)SEQ * DMODEL, (long)SEQ * DMODEL, (long)SEQ * SEQ);

    // --- softmax rows in place + fused bf16 emit
    softmax_kernel<<<dim3(BATCH * SEQ), 256, 0, stream>>>(attn_out, attn_bf);

    // --- v -> v^T bf16
    transpose_convert_kernel<<<dim3(DMODEL / 32, SEQ / 32, BATCH), dim3(32, 8), 0, stream>>>(
        v, vT, SEQ, DMODEL, (long)SEQ * DMODEL, (long)SEQ * DMODEL);

    // --- ctx^T = (attn @ v)^T  (8-phase 256x128 variant: grid 8x8x4 = 256 wgs)
    gemm8p<false, 128, false, true><<<dim3(DMODEL / 128, SEQ / 256, BATCH), 512, 0, stream>>>(
        attn_bf, nullptr, vT, nullptr, ctx_out, SEQ, DMODEL, SEQ, SEQ, 1.0f,
        (long)SEQ * SEQ, (long)SEQ * DMODEL, (long)SEQ * DMODEL);
}

// Round 2
// 406.781 us; speedup vs baseline: 1.1072x; 1.0219x over previous
//
#include <hip/hip_runtime.h>
#include <hip/hip_bf16.h>
#include <math.h>

#define BATCH 4
#define SEQ   2048
#define DMODEL 1024

typedef __attribute__((ext_vector_type(8))) short bf16x8;
typedef __attribute__((ext_vector_type(4))) float floatx4;

// async 16B/lane global->LDS. lds pointer MUST be wave-uniform; dest = base + lane*16.
__device__ __forceinline__ void async_copy16(const void* g, void* lds) {
    __builtin_amdgcn_global_load_lds(
        reinterpret_cast<const unsigned int __attribute__((address_space(1)))*>(
            reinterpret_cast<unsigned long long>(g)),
        reinterpret_cast<unsigned int __attribute__((address_space(3)))*>(
            (unsigned int)reinterpret_cast<unsigned long long>(lds)),
        16, 0, 0);
}

#define SCHED_FENCE() __builtin_amdgcn_sched_barrier(0)

// ============================================================================
// 256-row GEMM, m201-style schedule with one-phase fragment read-ahead.
// C = (A @ B_storage^T + bias) * scale. A:[M,K] bf16 row-major (ASPLIT:
// K-concat across A0|A1, each [M,K/2]); B_storage:[N,KBB] with K-wrap.
// 512 thr = 8 waves (2Mx4N), BM=256, BK=32, 4-slot LDS ring, prefetch dist 3.
// Per phase: {issue next-phase ds_reads | stage | counted wait | barrier |
// setprio MFMA setprio}. vmcnt never 0 in steady state; lgkm throttles
// guarantee write-after-read safety for ring-slot reuse.
// ============================================================================

// --- hot tile, BN=256 (2 phases, 16 MFMA each) -------------------------------
#define TILE256(T, U) do {                                                      \
    constexpr int sl  = (U) & 3, sl1 = ((U) + 1) & 3, sl3 = ((U) + 3) & 3;      \
    constexpr int p = (U) & 1, p1 = ((U) + 1) & 1;                              \
    /* ph0: read set1(t) (A hi-half), stage A(t+3) */                           \
    _Pragma("unroll") for (int i = 0; i < 4; ++i) aH[i] = readA(sl, 4 + i);     \
    stageA((T) + 3, 0, sl3); stageA((T) + 3, 1, sl3);                           \
    asm volatile("s_waitcnt vmcnt(6)" ::: "memory");                            \
    __builtin_amdgcn_s_barrier(); SCHED_FENCE();                                \
    __builtin_amdgcn_s_setprio(1);                                              \
    _Pragma("unroll") for (int i = 0; i < 4; ++i)                               \
      _Pragma("unroll") for (int j = 0; j < 4; ++j)                             \
        acc[i][j] = __builtin_amdgcn_mfma_f32_16x16x32_bf16(aP[p][i], bP[p][j], acc[i][j], 0, 0, 0); \
    __builtin_amdgcn_s_setprio(0);                                              \
    /* ph1: read set0(t+1), stage B(t+3) */                                     \
    _Pragma("unroll") for (int i = 0; i < 4; ++i) aP[p1][i] = readA(sl1, i);    \
    _Pragma("unroll") for (int j = 0; j < 4; ++j) bP[p1][j] = readB(sl1, j);    \
    stageB((T) + 3, 0, sl3); stageB((T) + 3, 1, sl3);                           \
    asm volatile("s_waitcnt lgkmcnt(8)" ::: "memory");                          \
    __builtin_amdgcn_s_barrier(); SCHED_FENCE();                                \
    __builtin_amdgcn_s_setprio(1);                                              \
    _Pragma("unroll") for (int i = 0; i < 4; ++i)                               \
      _Pragma("unroll") for (int j = 0; j < 4; ++j)                             \
        acc[4 + i][j] = __builtin_amdgcn_mfma_f32_16x16x32_bf16(aH[i], bP[p][j], acc[4 + i][j], 0, 0, 0); \
    __builtin_amdgcn_s_setprio(0);                                              \
} while (0)

#define DRAIN256(U, LAST) do {                                                  \
    constexpr int sl = (U) & 3, sl1 = ((U) + 1) & 3;                            \
    constexpr int p = (U) & 1, p1 = ((U) + 1) & 1;                              \
    _Pragma("unroll") for (int i = 0; i < 4; ++i) aH[i] = readA(sl, 4 + i);     \
    _Pragma("unroll") for (int i = 0; i < 4; ++i)                               \
      _Pragma("unroll") for (int j = 0; j < 4; ++j)                             \
        acc[i][j] = __builtin_amdgcn_mfma_f32_16x16x32_bf16(aP[p][i], bP[p][j], acc[i][j], 0, 0, 0); \
    if constexpr (!(LAST)) {                                                    \
        _Pragma("unroll") for (int i = 0; i < 4; ++i) aP[p1][i] = readA(sl1, i);\
        _Pragma("unroll") for (int j = 0; j < 4; ++j) bP[p1][j] = readB(sl1, j);\
    }                                                                           \
    _Pragma("unroll") for (int i = 0; i < 4; ++i)                               \
      _Pragma("unroll") for (int j = 0; j < 4; ++j)                             \
        acc[4 + i][j] = __builtin_amdgcn_mfma_f32_16x16x32_bf16(aH[i], bP[p][j], acc[4 + i][j], 0, 0, 0); \
} while (0)

// --- hot tile, BN=128 (1 phase, 16 MFMA) ------------------------------------
#define TILE128(T, U) do {                                                      \
    constexpr int sl1 = ((U) + 1) & 3, sl3 = ((U) + 3) & 3;                     \
    constexpr int p = (U) & 1, p1 = ((U) + 1) & 1;                              \
    asm volatile("s_waitcnt vmcnt(3)" ::: "memory");                            \
    __builtin_amdgcn_s_barrier(); SCHED_FENCE();                                \
    _Pragma("unroll") for (int i = 0; i < 8; ++i) aP[p1][i] = readA(sl1, i);    \
    _Pragma("unroll") for (int j = 0; j < 2; ++j) bP[p1][j] = readB(sl1, j);    \
    stageA((T) + 3, 0, sl3); stageA((T) + 3, 1, sl3); stageB((T) + 3, 0, sl3);  \
    asm volatile("s_waitcnt lgkmcnt(10)" ::: "memory");                         \
    __builtin_amdgcn_s_barrier(); SCHED_FENCE();                                \
    __builtin_amdgcn_s_setprio(1);                                              \
    _Pragma("unroll") for (int i = 0; i < 8; ++i)                               \
      _Pragma("unroll") for (int j = 0; j < 2; ++j)                             \
        acc[i][j] = __builtin_amdgcn_mfma_f32_16x16x32_bf16(aP[p][i], bP[p][j], acc[i][j], 0, 0, 0); \
    __builtin_amdgcn_s_setprio(0);                                              \
} while (0)

#define DRAIN128(U, LAST) do {                                                  \
    constexpr int sl1 = ((U) + 1) & 3;                                          \
    constexpr int p = (U) & 1, p1 = ((U) + 1) & 1;                              \
    if constexpr (!(LAST)) {                                                    \
        _Pragma("unroll") for (int i = 0; i < 8; ++i) aP[p1][i] = readA(sl1, i);\
        _Pragma("unroll") for (int j = 0; j < 2; ++j) bP[p1][j] = readB(sl1, j);\
    }                                                                           \
    _Pragma("unroll") for (int i = 0; i < 8; ++i)                               \
      _Pragma("unroll") for (int j = 0; j < 2; ++j)                             \
        acc[i][j] = __builtin_amdgcn_mfma_f32_16x16x32_bf16(aP[p][i], bP[p][j], acc[i][j], 0, 0, 0); \
} while (0)

template<bool ASPLIT, int BN, bool HAS_BIAS, int MM, int NN, int KK, int KBB>
__global__ __launch_bounds__(512, 1)
void gemm8p(const __hip_bfloat16* __restrict__ A0, const __hip_bfloat16* __restrict__ A1,
            const __hip_bfloat16* __restrict__ B, const float* __restrict__ bias,
            float* __restrict__ C, float scale, long sAb, long sBb, long sCb)
{
    constexpr int BM = 256, BK = 32;
    constexpr int NT = KK / BK;
    constexpr int KA = ASPLIT ? (KK / 2) : KK;     // per-source A row stride
    constexpr int WN = BN / 4, NF = WN / 16;
    constexpr int SLOT_A = BM * BK, SLOT_B = BN * BK;
    constexpr int GX = NN / BN, GY = MM / BM;
    constexpr int CPX = (GX * GY) / 8;
    static_assert(NT % 4 == 0 && NT >= 8, "");
    static_assert((GX * GY) % 8 == 0, "");

    __shared__ __align__(16) __hip_bfloat16 sA[4][SLOT_A];
    __shared__ __align__(16) __hip_bfloat16 sB[4][SLOT_B];

    const int bz = blockIdx.z;
    A0 += (long)bz * sAb;
    if (ASPLIT) A1 += (long)bz * sAb;
    B += (long)bz * sBb;
    C += (long)bz * sCb;

    // T1: XCD-bijective block swizzle (wgs per z-slice divisible by 8)
    int b = blockIdx.y * GX + blockIdx.x;
    b = (b & 7) * CPX + (b >> 3);
    const int col0 = (b % GX) * BN;
    const int row0 = (b / GX) * BM;

    const int tid  = threadIdx.x;
    const int wave = tid >> 6, lane = tid & 63;
    const int wm = wave >> 2, wn = wave & 3;       // 2 x 4 wave grid
    const int fr = lane & 15, fq = lane >> 4;      // fragment row / k-quad
    const int swz = (fq ^ ((fr >> 1) & 3)) << 3;   // read-side chunk swizzle (elems)

    // staging: one call = 128 rows x 32 cols (8 KB) = 512 thr x 16 B
    const int s_r  = (wave << 4) + (lane >> 2);
    const int s_c4 = lane & 3;

    auto stageA = [&](int t, int c, int sl) {
        const int lr = (c << 7) + s_r;
        const int ch = (s_c4 ^ ((lr >> 1) & 3)) << 3;   // pre-swizzled global chunk
        int k0 = t << 5;
        const __hip_bfloat16* src = A0;
        if (ASPLIT && k0 >= KA) { src = A1; k0 -= KA; }
        async_copy16(src + (long)(row0 + lr) * KA + k0 + ch,
                     &sA[sl][((c << 7) + (wave << 4)) * BK]);
    };
    auto stageB = [&](int t, int c, int sl) {
        const int lr = (c << 7) + s_r;
        const int ch = (s_c4 ^ ((lr >> 1) & 3)) << 3;
        const int k0 = (t << 5) & (KBB - 1);            // K-wrap for concat trick
        async_copy16(B + (long)(col0 + lr) * KBB + k0 + ch,
                     &sB[sl][((c << 7) + (wave << 4)) * BK]);
    };
    auto readA = [&](int sl, int i) -> bf16x8 {
        return *(const bf16x8*)&sA[sl][((wm << 7) + (i << 4) + fr) * BK + swz];
    };
    auto readB = [&](int sl, int j) -> bf16x8 {
        return *(const bf16x8*)&sB[sl][(wn * WN + (j << 4) + fr) * BK + swz];
    };

    floatx4 acc[8][NF];
    #pragma unroll
    for (int i = 0; i < 8; ++i)
        #pragma unroll
        for (int j = 0; j < NF; ++j) acc[i][j] = (floatx4){0.f, 0.f, 0.f, 0.f};

    bf16x8 aP[2][BN == 256 ? 4 : 8];   // read-ahead fragment double buffer
    bf16x8 bP[2][NF];
    bf16x8 aH[BN == 256 ? 4 : 1];      // same-tile hi-half (256 path only)

    if constexpr (BN == 256) {
        // prologue: stage tiles 0..2, pre-read set0(0)
        stageA(0, 0, 0); stageA(0, 1, 0); stageB(0, 0, 0); stageB(0, 1, 0);
        stageA(1, 0, 1); stageA(1, 1, 1); stageB(1, 0, 1); stageB(1, 1, 1);
        stageA(2, 0, 2); stageA(2, 1, 2); stageB(2, 0, 2); stageB(2, 1, 2);
        asm volatile("s_waitcnt vmcnt(8)" ::: "memory");
        __builtin_amdgcn_s_barrier(); SCHED_FENCE();
        #pragma unroll
        for (int i = 0; i < 4; ++i) aP[0][i] = readA(0, i);
        #pragma unroll
        for (int j = 0; j < 4; ++j) bP[0][j] = readB(0, j);

        #pragma unroll 1
        for (int tt = 0; tt < NT - 4; tt += 4) {
            TILE256(tt + 0, 0); TILE256(tt + 1, 1); TILE256(tt + 2, 2); TILE256(tt + 3, 3);
        }
        TILE256(NT - 4, 0);
        asm volatile("s_waitcnt vmcnt(0)" ::: "memory");
        __builtin_amdgcn_s_barrier(); SCHED_FENCE();
        DRAIN256(1, false); DRAIN256(2, false); DRAIN256(3, true);
    } else {
        stageA(0, 0, 0); stageA(0, 1, 0); stageB(0, 0, 0);
        stageA(1, 0, 1); stageA(1, 1, 1); stageB(1, 0, 1);
        stageA(2, 0, 2); stageA(2, 1, 2); stageB(2, 0, 2);
        asm volatile("s_waitcnt vmcnt(6)" ::: "memory");
        __builtin_amdgcn_s_barrier(); SCHED_FENCE();
        #pragma unroll
        for (int i = 0; i < 8; ++i) aP[0][i] = readA(0, i);
        #pragma unroll
        for (int j = 0; j < 2; ++j) bP[0][j] = readB(0, j);

        #pragma unroll 1
        for (int tt = 0; tt < NT - 4; tt += 4) {
            TILE128(tt + 0, 0); TILE128(tt + 1, 1); TILE128(tt + 2, 2); TILE128(tt + 3, 3);
        }
        TILE128(NT - 4, 0);
        asm volatile("s_waitcnt vmcnt(0)" ::: "memory");
        __builtin_amdgcn_s_barrier(); SCHED_FENCE();
        DRAIN128(1, false); DRAIN128(2, false); DRAIN128(3, true);
    }

    // epilogue — C/D layout: col = lane&15, row = (lane>>4)*4 + reg (row-major out)
    #pragma unroll
    for (int i = 0; i < 8; ++i) {
        #pragma unroll
        for (int r = 0; r < 4; ++r) {
            const int row = row0 + (wm << 7) + (i << 4) + (fq << 2) + r;
            #pragma unroll
            for (int j = 0; j < NF; ++j) {
                const int col = col0 + wn * WN + (j << 4) + fr;
                float val = acc[i][j][r];
                if (HAS_BIAS) val += bias[(long)row * NN + col];
                val *= scale;
                C[(long)row * NN + col] = val;
            }
        }
    }
}

// ============================================================================
// legacy 128^2 GEMM (kept for qpe/kpe and biasM: small shapes, 256-wg grids)
// ============================================================================
template<bool SPLIT_A, bool HAS_BIAS, bool OUT_TRANS, bool OUT_BF16>
__global__ __launch_bounds__(256, 1)
void mfma_gemm(const __hip_bfloat16* __restrict__ Ah, const __hip_bfloat16* __restrict__ Al,
               const __hip_bfloat16* __restrict__ Bh,
               const float* __restrict__ bias, void* __restrict__ Cvoid,
               int M, int N, int K, float scale,
               long sAb, long sBb, long sCb)
{
    constexpr int NA = SPLIT_A ? 2 : 1;
    __shared__ __align__(16) __hip_bfloat16 sA[NA][128 * 32];
    __shared__ __align__(16) __hip_bfloat16 sB[128 * 32];

    const int bz = blockIdx.z;
    Ah += (long)bz * sAb;
    Bh += (long)bz * sBb;
    if (SPLIT_A) Al += (long)bz * sAb;

    const int row0 = blockIdx.y * 128;
    const int col0 = blockIdx.x * 128;
    const int tid  = threadIdx.x;
    const int wave = tid >> 6;
    const int lane = tid & 63;

    const int srow   = wave * 16 + (lane >> 2);
    const int schunk = (lane & 3) * 8;

    const int wm = (wave >> 1) * 64;
    const int wn = (wave & 1) * 64;
    const int fr = lane & 15;
    const int fk = (lane >> 4) * 8;

    const floatx4 zero = {0.f, 0.f, 0.f, 0.f};
    floatx4 acc[4][4];
    #pragma unroll
    for (int i = 0; i < 4; ++i)
        #pragma unroll
        for (int j = 0; j < 4; ++j) acc[i][j] = zero;

    for (int k0 = 0; k0 < K; k0 += 32) {
        #pragma unroll
        for (int t = 0; t < 2; ++t) {
            const long arow = (long)(row0 + t * 64 + srow);
            const long brow = (long)(col0 + t * 64 + srow);
            const int  soff = (t * 64 + wave * 16) * 32;
            async_copy16(Ah + arow * K + k0 + schunk, &sA[0][soff]);
            async_copy16(Bh + brow * K + k0 + schunk, &sB[soff]);
            if (SPLIT_A)
                async_copy16(Al + arow * K + k0 + schunk, &sA[NA - 1][soff]);
        }
        __syncthreads();

        bf16x8 aH[4], bH[4];
        #pragma unroll
        for (int i = 0; i < 4; ++i) aH[i] = *(const bf16x8*)&sA[0][(wm + i * 16 + fr) * 32 + fk];
        #pragma unroll
        for (int j = 0; j < 4; ++j) bH[j] = *(const bf16x8*)&sB[(wn + j * 16 + fr) * 32 + fk];

        if (SPLIT_A) {
            bf16x8 aL[4];
            #pragma unroll
            for (int i = 0; i < 4; ++i) aL[i] = *(const bf16x8*)&sA[NA - 1][(wm + i * 16 + fr) * 32 + fk];
            #pragma unroll
            for (int i = 0; i < 4; ++i)
                #pragma unroll
                for (int j = 0; j < 4; ++j) {
                    acc[i][j] = __builtin_amdgcn_mfma_f32_16x16x32_bf16(aH[i], bH[j], acc[i][j], 0, 0, 0);
                    acc[i][j] = __builtin_amdgcn_mfma_f32_16x16x32_bf16(aL[i], bH[j], acc[i][j], 0, 0, 0);
                }
        } else {
            #pragma unroll
            for (int i = 0; i < 4; ++i)
                #pragma unroll
                for (int j = 0; j < 4; ++j)
                    acc[i][j] = __builtin_amdgcn_mfma_f32_16x16x32_bf16(aH[i], bH[j], acc[i][j], 0, 0, 0);
        }
        __syncthreads();
    }

    float* Cf = (float*)Cvoid + (long)bz * sCb;
    __hip_bfloat16* Cb = (__hip_bfloat16*)Cvoid + (long)bz * sCb;
    #pragma unroll
    for (int i = 0; i < 4; ++i) {
        #pragma unroll
        for (int r = 0; r < 4; ++r) {
            const int row = row0 + wm + i * 16 + (lane >> 4) * 4 + r;
            #pragma unroll
            for (int j = 0; j < 4; ++j) {
                const int col = col0 + wn + j * 16 + (lane & 15);
                float val = acc[i][j][r];
                if (HAS_BIAS) val += bias[(long)row * N + col];
                val *= scale;
                if (OUT_BF16)       Cb[(long)row * N + col] = __float2bfloat16(val);
                else if (OUT_TRANS) Cf[(long)col * M + row] = val;
                else                Cf[(long)row * N + col] = val;
            }
        }
    }
}

// fp32 -> bf16, 4 elems/thread
__global__ __launch_bounds__(256)
void convert_bf16_kernel(const float* __restrict__ in, __hip_bfloat16* __restrict__ out, long n)
{
    const long i = ((long)blockIdx.x * 256 + threadIdx.x) * 4;
    if (i >= n) return;
    float va[4];
    *(float4*)va = *(const float4*)(in + i);
    __align__(8) __hip_bfloat16 h[4];
    #pragma unroll
    for (int j = 0; j < 4; ++j) h[j] = __float2bfloat16(va[j]);
    *(uint2*)(out + i) = *(uint2*)h;
}

// fp32 -> (hi, lo) bf16 pair: hi = bf16(x), lo = bf16(x - float(hi))
__global__ __launch_bounds__(256)
void split_convert_kernel(const float* __restrict__ in, __hip_bfloat16* __restrict__ hi,
                          __hip_bfloat16* __restrict__ lo, long n)
{
    const long i = ((long)blockIdx.x * 256 + threadIdx.x) * 4;
    if (i >= n) return;
    float va[4];
    *(float4*)va = *(const float4*)(in + i);
    __align__(8) __hip_bfloat16 h[4], l[4];
    #pragma unroll
    for (int j = 0; j < 4; ++j) {
        h[j] = __float2bfloat16(va[j]);
        l[j] = __float2bfloat16(va[j] - __bfloat162float(h[j]));
    }
    *(uint2*)(hi + i) = *(uint2*)h;
    *(uint2*)(lo + i) = *(uint2*)l;
}

// in [R][C] fp32 -> out [C][R] bf16 (batched via blockIdx.z)
__global__ __launch_bounds__(256)
void transpose_convert_kernel(const float* __restrict__ in, __hip_bfloat16* __restrict__ out,
                              int R, int C, long sIn, long sOut)
{
    in  += (long)blockIdx.z * sIn;
    out += (long)blockIdx.z * sOut;
    __shared__ float t[32][33];
    const int c0 = blockIdx.x * 32, r0 = blockIdx.y * 32;
    for (int i = threadIdx.y; i < 32; i += 8)
        t[i][threadIdx.x] = in[(long)(r0 + i) * C + c0 + threadIdx.x];
    __syncthreads();
    for (int i = threadIdx.y; i < 32; i += 8)
        out[(long)(c0 + i) * R + r0 + threadIdx.x] = __float2bfloat16(t[threadIdx.x][i]);
}

// in-place row softmax over rows of length SEQ; also emits bf16 copy.
__global__ __launch_bounds__(256)
void softmax_kernel(float* __restrict__ data, __hip_bfloat16* __restrict__ data_bf)
{
    const long row = blockIdx.x;
    float* p = data + row * (long)SEQ;
    __hip_bfloat16* pb = data_bf + row * (long)SEQ;
    const int tid = threadIdx.x;
    const int PER = SEQ / 256;  // 8

    float v[PER];
    float m = -1e30f;
    #pragma unroll
    for (int i = 0; i < PER; ++i) {
        v[i] = p[tid + i * 256];
        m = fmaxf(m, v[i]);
    }
    __shared__ float red[256];
    red[tid] = m;
    __syncthreads();
    #pragma unroll
    for (int s = 128; s > 0; s >>= 1) {
        if (tid < s) red[tid] = fmaxf(red[tid], red[tid + s]);
        __syncthreads();
    }
    m = red[0];
    __syncthreads();
    float sum = 0.f;
    #pragma unroll
    for (int i = 0; i < PER; ++i) {
        v[i] = __expf(v[i] - m);
        sum += v[i];
    }
    red[tid] = sum;
    __syncthreads();
    #pragma unroll
    for (int s = 128; s > 0; s >>= 1) {
        if (tid < s) red[tid] += red[tid + s];
        __syncthreads();
    }
    const float inv = 1.0f / red[0];
    #pragma unroll
    for (int i = 0; i < PER; ++i) {
        const float a = v[i] * inv;
        p[tid + i * 256]  = a;
        pb[tid + i * 256] = __float2bfloat16(a);
    }
}

extern "C" void kernel_launch(void* const* d_in, const int* in_sizes, int n_in,
                              void* d_out, int out_size, void* d_ws, size_t ws_size,
                              hipStream_t stream)
{
    const float* q  = (const float*)d_in[0];   // [4, 2048, 1024]
    const float* k  = (const float*)d_in[1];
    const float* v  = (const float*)d_in[2];
    const float* pe = (const float*)d_in[3];   // [10000, 1024], first 2048 rows used
    const float* Uq = (const float*)d_in[4];   // [1024, 1024] (x @ Uq)
    const float* Uk = (const float*)d_in[5];

    float* out      = (float*)d_out;
    float* ctx_out  = out;                                   // [4][1024][2048] (context^T per batch)
    float* attn_out = out + (long)BATCH * SEQ * DMODEL;      // [4][2048][2048]

    const long SD = (long)BATCH * SEQ * DMODEL;   // 8.4M elems
    char* w = (char*)d_ws;
    __hip_bfloat16* q_hi  = (__hip_bfloat16*)w;  w += SD * 2;
    __hip_bfloat16* q_lo  = (__hip_bfloat16*)w;  w += SD * 2;
    __hip_bfloat16* k_bf  = (__hip_bfloat16*)w;  w += SD * 2;
    __hip_bfloat16* pe_bf = (__hip_bfloat16*)w;  w += (long)SEQ * DMODEL * 2;
    __hip_bfloat16* UqT   = (__hip_bfloat16*)w;  w += (long)DMODEL * DMODEL * 2;  // UqT/UkT contiguous
    __hip_bfloat16* UkT   = (__hip_bfloat16*)w;  w += (long)DMODEL * DMODEL * 2;
    __hip_bfloat16* qpe_bf= (__hip_bfloat16*)w;  w += (long)SEQ * DMODEL * 2;     // qpe/kpe contiguous
    __hip_bfloat16* kpe_bf= (__hip_bfloat16*)w;  w += (long)SEQ * DMODEL * 2;
    float*          biasM = (float*)w;           w += (long)SEQ * SEQ * 4;
    // aliases (lifetimes disjoint, stream-ordered):
    __hip_bfloat16* attn_bf = q_hi;   // 33.5M elems needed = q_hi+q_lo region; written by softmax
    __hip_bfloat16* vT      = k_bf;   // 8.4M elems = k_bf region; written after scores GEMM

    const float inv_scale = 1.0f / sqrtf(128.0f);

    // --- conversions
    convert_bf16_kernel<<<dim3((SEQ * DMODEL) / 4 / 256), 256, 0, stream>>>(pe, pe_bf, (long)SEQ * DMODEL);
    transpose_convert_kernel<<<dim3(DMODEL / 32, DMODEL / 32, 1), dim3(32, 8), 0, stream>>>(
        Uq, UqT, DMODEL, DMODEL, 0, 0);
    transpose_convert_kernel<<<dim3(DMODEL / 32, DMODEL / 32, 1), dim3(32, 8), 0, stream>>>(
        Uk, UkT, DMODEL, DMODEL, 0, 0);
    split_convert_kernel<<<dim3(SD / 4 / 256), 256, 0, stream>>>(q, q_hi, q_lo, SD);
    convert_bf16_kernel<<<dim3(SD / 4 / 256), 256, 0, stream>>>(k, k_bf, SD);

    // --- qpe = pe @ Uq, kpe = pe @ Uk  (one batched launch, bf16 out; legacy kernel)
    mfma_gemm<false, false, false, true><<<dim3(DMODEL / 128, SEQ / 128, 2), 256, 0, stream>>>(
        pe_bf, nullptr, UqT, nullptr, qpe_bf, SEQ, DMODEL, DMODEL, 1.0f,
        0, (long)DMODEL * DMODEL, (long)SEQ * DMODEL);

    // --- biasM = qpe @ kpe^T (fp32; legacy kernel)
    mfma_gemm<false, false, false, false><<<dim3(SEQ / 128, SEQ / 128, 1), 256, 0, stream>>>(
        qpe_bf, nullptr, kpe_bf, nullptr, biasM, SEQ, SEQ, DMODEL, 1.0f, 0, 0, 0);

    // --- scores = ((q_hi+q_lo) @ k^T + biasM) * inv_scale
    //     K-concat split: A = [q_hi | q_lo] (K=2048), B = k wrapped (Kb=1024).
    gemm8p<true, 256, true, 2048, 2048, 2048, 1024>
        <<<dim3(SEQ / 256, SEQ / 256, BATCH), 512, 0, stream>>>(
        q_hi, q_lo, k_bf, biasM, attn_out, inv_scale,
        (long)SEQ * DMODEL, (long)SEQ * DMODEL, (long)SEQ * SEQ);

    // --- softmax rows in place + fused bf16 emit
    softmax_kernel<<<dim3(BATCH * SEQ), 256, 0, stream>>>(attn_out, attn_bf);

    // --- v -> v^T bf16
    transpose_convert_kernel<<<dim3(DMODEL / 32, SEQ / 32, BATCH), dim3(32, 8), 0, stream>>>(
        v, vT, SEQ, DMODEL, (long)SEQ * DMODEL, (long)SEQ * DMODEL);

    // --- ctx^T[d][i] = sum_k vT[d][k] * attn[i][k]  (A = vT, B = attn_bf;
    //     row-major coalesced stores into the required [4][1024][2048] layout)
    gemm8p<false, 128, false, 1024, 2048, 2048, 2048>
        <<<dim3(SEQ / 128, DMODEL / 256, BATCH), 512, 0, stream>>>(
        vT, nullptr, attn_bf, nullptr, ctx_out, 1.0f,
        (long)SEQ * DMODEL, (long)SEQ * SEQ, (long)SEQ * DMODEL);
}

// Round 4
// 400.000 us; speedup vs baseline: 1.1260x; 1.0170x over previous
//
#include <hip/hip_runtime.h>
#include <hip/hip_bf16.h>
#include <math.h>

#define BATCH 4
#define SEQ   2048
#define DMODEL 1024

typedef __attribute__((ext_vector_type(8))) short bf16x8;
typedef __attribute__((ext_vector_type(4))) float floatx4;

// async 16B/lane global->LDS. lds pointer MUST be wave-uniform; dest = base + lane*16.
__device__ __forceinline__ void async_copy16(const void* g, void* lds) {
    __builtin_amdgcn_global_load_lds(
        reinterpret_cast<const unsigned int __attribute__((address_space(1)))*>(
            reinterpret_cast<unsigned long long>(g)),
        reinterpret_cast<unsigned int __attribute__((address_space(3)))*>(
            (unsigned int)reinterpret_cast<unsigned long long>(lds)),
        16, 0, 0);
}

#define SCHED_FENCE() __builtin_amdgcn_sched_barrier(0)

// ============================================================================
// 256-row GEMM, single-barrier-per-K-tile schedule.
// C = (A @ B_storage^T + bias) * scale. A:[M,K] bf16 row-major (ASPLIT:
// K-concat across A0|A1, each [M,K/2]); B_storage:[N,KBB] with K-wrap.
// 512 thr = 8 waves (2Mx4N), BM=256, BK=32, 4-slot LDS ring, prefetch dist 3.
//
// Safety argument for ONE barrier per tile:
//  - WAR: stage(t+3) writes slot (t-1)&3. All reads of slot t-1 are drained
//    by the counted lgkm waits inside tile t-1 (before BAR(t)); stage(t+3)
//    issues after BAR(t). Barrier separates them.
//  - cross-wave RAW: read-ahead of slot t+1 (issued inside tile t) requires
//    ALL waves' loads of t+1 landed. Each wave executes vmcnt(force t+1)
//    before BAR(t-1); the barrier publishes it.
// vmcnt never drains to 0 in steady state; lgkm counts are exact.
// ============================================================================

// --- K-tile, BN=256 (32 MFMA split in 2 clusters of 16) ----------------------
#define T256(T, U, STG, RA, VMM, BARR) do {                                     \
    constexpr int sl = (U) & 3, sl1 = ((U) + 1) & 3, sl3 = ((U) + 3) & 3;       \
    constexpr int p = (U) & 1, p1 = ((U) + 1) & 1;                              \
    _Pragma("unroll") for (int i = 0; i < 4; ++i) aH[i] = readA(sl, 4 + i);     \
    if constexpr (STG) { stageA((T) + 3, 0, sl3); stageA((T) + 3, 1, sl3);      \
                         stageB((T) + 3, 0, sl3); stageB((T) + 3, 1, sl3); }    \
    asm volatile("s_waitcnt lgkmcnt(4)" ::: "memory"); SCHED_FENCE();           \
    __builtin_amdgcn_s_setprio(1);                                              \
    _Pragma("unroll") for (int i = 0; i < 4; ++i)                               \
      _Pragma("unroll") for (int j = 0; j < 4; ++j)                             \
        acc[i][j] = __builtin_amdgcn_mfma_f32_16x16x32_bf16(aP[p][i], bP[p][j], acc[i][j], 0, 0, 0); \
    __builtin_amdgcn_s_setprio(0);                                              \
    if constexpr (RA) {                                                         \
        _Pragma("unroll") for (int i = 0; i < 4; ++i) aP[p1][i] = readA(sl1, i);\
        _Pragma("unroll") for (int j = 0; j < 4; ++j) bP[p1][j] = readB(sl1, j);\
        asm volatile("s_waitcnt lgkmcnt(8)" ::: "memory");                      \
    } else {                                                                    \
        asm volatile("s_waitcnt lgkmcnt(0)" ::: "memory");                      \
    }                                                                           \
    SCHED_FENCE();                                                              \
    __builtin_amdgcn_s_setprio(1);                                              \
    _Pragma("unroll") for (int i = 0; i < 4; ++i)                               \
      _Pragma("unroll") for (int j = 0; j < 4; ++j)                             \
        acc[4 + i][j] = __builtin_amdgcn_mfma_f32_16x16x32_bf16(aH[i], bP[p][j], acc[4 + i][j], 0, 0, 0); \
    __builtin_amdgcn_s_setprio(0);                                              \
    if constexpr ((VMM) == 2)      { asm volatile("s_waitcnt vmcnt(4)" ::: "memory"); } \
    else if constexpr ((VMM) == 1) { asm volatile("s_waitcnt vmcnt(0)" ::: "memory"); } \
    if constexpr (BARR) __builtin_amdgcn_s_barrier();                           \
} while (0)

// --- K-tile, BN=128 (16 MFMA, all operands read-ahead) -----------------------
#define T128(T, U, STG, RA, VMM, BARR) do {                                     \
    constexpr int sl1 = ((U) + 1) & 3, sl3 = ((U) + 3) & 3;                     \
    constexpr int p = (U) & 1, p1 = ((U) + 1) & 1;                              \
    if constexpr (RA) {                                                         \
        _Pragma("unroll") for (int i = 0; i < 8; ++i) aP[p1][i] = readA(sl1, i);\
        _Pragma("unroll") for (int j = 0; j < 2; ++j) bP[p1][j] = readB(sl1, j);\
    }                                                                           \
    if constexpr (STG) { stageA((T) + 3, 0, sl3); stageA((T) + 3, 1, sl3);      \
                         stageB((T) + 3, 0, sl3); }                             \
    if constexpr (RA) { asm volatile("s_waitcnt lgkmcnt(10)" ::: "memory"); }   \
    else              { asm volatile("s_waitcnt lgkmcnt(0)" ::: "memory"); }    \
    SCHED_FENCE();                                                              \
    __builtin_amdgcn_s_setprio(1);                                              \
    _Pragma("unroll") for (int i = 0; i < 8; ++i)                               \
      _Pragma("unroll") for (int j = 0; j < 2; ++j)                             \
        acc[i][j] = __builtin_amdgcn_mfma_f32_16x16x32_bf16(aP[p][i], bP[p][j], acc[i][j], 0, 0, 0); \
    __builtin_amdgcn_s_setprio(0);                                              \
    if constexpr ((VMM) == 2)      { asm volatile("s_waitcnt vmcnt(3)" ::: "memory"); } \
    else if constexpr ((VMM) == 1) { asm volatile("s_waitcnt vmcnt(0)" ::: "memory"); } \
    if constexpr (BARR) __builtin_amdgcn_s_barrier();                           \
} while (0)

template<bool ASPLIT, int BN, bool HAS_BIAS, int MM, int NN, int KK, int KBB>
__global__ __launch_bounds__(512, 1)
void gemm8p(const __hip_bfloat16* __restrict__ A0, const __hip_bfloat16* __restrict__ A1,
            const __hip_bfloat16* __restrict__ B, const float* __restrict__ bias,
            float* __restrict__ C, float scale, long sAb, long sBb, long sCb)
{
    constexpr int BM = 256, BK = 32;
    constexpr int NT = KK / BK;
    constexpr int KA = ASPLIT ? (KK / 2) : KK;     // per-source A row stride
    constexpr int WN = BN / 4, NF = WN / 16;
    constexpr int SLOT_A = BM * BK, SLOT_B = BN * BK;
    constexpr int GX = NN / BN, GY = MM / BM;
    constexpr int CPX = (GX * GY) / 8;
    static_assert(NT % 4 == 0 && NT >= 8, "");
    static_assert((GX * GY) % 8 == 0, "");

    __shared__ __align__(16) __hip_bfloat16 sA[4][SLOT_A];
    __shared__ __align__(16) __hip_bfloat16 sB[4][SLOT_B];

    const int bz = blockIdx.z;
    A0 += (long)bz * sAb;
    if (ASPLIT) A1 += (long)bz * sAb;
    B += (long)bz * sBb;
    C += (long)bz * sCb;

    // T1: XCD-bijective block swizzle (wgs per z-slice divisible by 8)
    int b = blockIdx.y * GX + blockIdx.x;
    b = (b & 7) * CPX + (b >> 3);
    const int col0 = (b % GX) * BN;
    const int row0 = (b / GX) * BM;

    const int tid  = threadIdx.x;
    const int wave = tid >> 6, lane = tid & 63;
    const int wm = wave >> 2, wn = wave & 3;       // 2 x 4 wave grid
    const int fr = lane & 15, fq = lane >> 4;      // fragment row / k-quad
    const int swz = (fq ^ ((fr >> 1) & 3)) << 3;   // read-side chunk swizzle (elems)

    // staging: one call = 128 rows x 32 cols (8 KB) = 512 thr x 16 B
    const int s_r  = (wave << 4) + (lane >> 2);
    const int s_c4 = lane & 3;

    auto stageA = [&](int t, int c, int sl) {
        const int lr = (c << 7) + s_r;
        const int ch = (s_c4 ^ ((lr >> 1) & 3)) << 3;   // pre-swizzled global chunk
        int k0 = t << 5;
        const __hip_bfloat16* src = A0;
        if (ASPLIT && k0 >= KA) { src = A1; k0 -= KA; }
        async_copy16(src + (long)(row0 + lr) * KA + k0 + ch,
                     &sA[sl][((c << 7) + (wave << 4)) * BK]);
    };
    auto stageB = [&](int t, int c, int sl) {
        const int lr = (c << 7) + s_r;
        const int ch = (s_c4 ^ ((lr >> 1) & 3)) << 3;
        const int k0 = (t << 5) & (KBB - 1);            // K-wrap for concat trick
        async_copy16(B + (long)(col0 + lr) * KBB + k0 + ch,
                     &sB[sl][((c << 7) + (wave << 4)) * BK]);
    };
    auto readA = [&](int sl, int i) -> bf16x8 {
        return *(const bf16x8*)&sA[sl][((wm << 7) + (i << 4) + fr) * BK + swz];
    };
    auto readB = [&](int sl, int j) -> bf16x8 {
        return *(const bf16x8*)&sB[sl][(wn * WN + (j << 4) + fr) * BK + swz];
    };

    floatx4 acc[8][NF];
    #pragma unroll
    for (int i = 0; i < 8; ++i)
        #pragma unroll
        for (int j = 0; j < NF; ++j) acc[i][j] = (floatx4){0.f, 0.f, 0.f, 0.f};

    bf16x8 aP[2][BN == 256 ? 4 : 8];   // read-ahead fragment double buffer
    bf16x8 bP[2][NF];
    bf16x8 aH[BN == 256 ? 4 : 1];      // same-tile hi-half (256 path only)

    if constexpr (BN == 256) {
        // prologue: stage tiles 0..2; force 0,1 resident; publish; pre-read slot 0
        stageA(0, 0, 0); stageA(0, 1, 0); stageB(0, 0, 0); stageB(0, 1, 0);
        stageA(1, 0, 1); stageA(1, 1, 1); stageB(1, 0, 1); stageB(1, 1, 1);
        stageA(2, 0, 2); stageA(2, 1, 2); stageB(2, 0, 2); stageB(2, 1, 2);
        asm volatile("s_waitcnt vmcnt(4)" ::: "memory");
        __builtin_amdgcn_s_barrier(); SCHED_FENCE();
        #pragma unroll
        for (int i = 0; i < 4; ++i) aP[0][i] = readA(0, i);
        #pragma unroll
        for (int j = 0; j < 4; ++j) bP[0][j] = readB(0, j);

        #pragma unroll 1
        for (int tt = 0; tt < NT - 4; tt += 4) {
            T256(tt + 0, 0, 1, 1, 2, 1); T256(tt + 1, 1, 1, 1, 2, 1);
            T256(tt + 2, 2, 1, 1, 2, 1); T256(tt + 3, 3, 1, 1, 2, 1);
        }
        T256(NT - 4, 0, 1, 1, 2, 1);   // stages NT-1
        T256(NT - 3, 1, 0, 1, 1, 1);   // drain vmcnt(0): slot NT-1 resident
        T256(NT - 2, 2, 0, 1, 0, 0);
        T256(NT - 1, 3, 0, 0, 0, 0);
    } else {
        stageA(0, 0, 0); stageA(0, 1, 0); stageB(0, 0, 0);
        stageA(1, 0, 1); stageA(1, 1, 1); stageB(1, 0, 1);
        stageA(2, 0, 2); stageA(2, 1, 2); stageB(2, 0, 2);
        asm volatile("s_waitcnt vmcnt(3)" ::: "memory");
        __builtin_amdgcn_s_barrier(); SCHED_FENCE();
        #pragma unroll
        for (int i = 0; i < 8; ++i) aP[0][i] = readA(0, i);
        #pragma unroll
        for (int j = 0; j < 2; ++j) bP[0][j] = readB(0, j);

        #pragma unroll 1
        for (int tt = 0; tt < NT - 4; tt += 4) {
            T128(tt + 0, 0, 1, 1, 2, 1); T128(tt + 1, 1, 1, 1, 2, 1);
            T128(tt + 2, 2, 1, 1, 2, 1); T128(tt + 3, 3, 1, 1, 2, 1);
        }
        T128(NT - 4, 0, 1, 1, 2, 1);
        T128(NT - 3, 1, 0, 1, 1, 1);
        T128(NT - 2, 2, 0, 1, 0, 0);
        T128(NT - 1, 3, 0, 0, 0, 0);
    }

    // epilogue — C/D layout: col = lane&15, row = (lane>>4)*4 + reg (row-major out)
    #pragma unroll
    for (int i = 0; i < 8; ++i) {
        #pragma unroll
        for (int r = 0; r < 4; ++r) {
            const int row = row0 + (wm << 7) + (i << 4) + (fq << 2) + r;
            #pragma unroll
            for (int j = 0; j < NF; ++j) {
                const int col = col0 + wn * WN + (j << 4) + fr;
                float val = acc[i][j][r];
                if (HAS_BIAS) val += bias[(long)row * NN + col];
                val *= scale;
                C[(long)row * NN + col] = val;
            }
        }
    }
}

// ============================================================================
// legacy 128^2 GEMM (kept for qpe/kpe and biasM: small shapes, 256-wg grids)
// ============================================================================
template<bool SPLIT_A, bool HAS_BIAS, bool OUT_TRANS, bool OUT_BF16>
__global__ __launch_bounds__(256, 1)
void mfma_gemm(const __hip_bfloat16* __restrict__ Ah, const __hip_bfloat16* __restrict__ Al,
               const __hip_bfloat16* __restrict__ Bh,
               const float* __restrict__ bias, void* __restrict__ Cvoid,
               int M, int N, int K, float scale,
               long sAb, long sBb, long sCb)
{
    constexpr int NA = SPLIT_A ? 2 : 1;
    __shared__ __align__(16) __hip_bfloat16 sA[NA][128 * 32];
    __shared__ __align__(16) __hip_bfloat16 sB[128 * 32];

    const int bz = blockIdx.z;
    Ah += (long)bz * sAb;
    Bh += (long)bz * sBb;
    if (SPLIT_A) Al += (long)bz * sAb;

    const int row0 = blockIdx.y * 128;
    const int col0 = blockIdx.x * 128;
    const int tid  = threadIdx.x;
    const int wave = tid >> 6;
    const int lane = tid & 63;

    const int srow   = wave * 16 + (lane >> 2);
    const int schunk = (lane & 3) * 8;

    const int wm = (wave >> 1) * 64;
    const int wn = (wave & 1) * 64;
    const int fr = lane & 15;
    const int fk = (lane >> 4) * 8;

    const floatx4 zero = {0.f, 0.f, 0.f, 0.f};
    floatx4 acc[4][4];
    #pragma unroll
    for (int i = 0; i < 4; ++i)
        #pragma unroll
        for (int j = 0; j < 4; ++j) acc[i][j] = zero;

    for (int k0 = 0; k0 < K; k0 += 32) {
        #pragma unroll
        for (int t = 0; t < 2; ++t) {
            const long arow = (long)(row0 + t * 64 + srow);
            const long brow = (long)(col0 + t * 64 + srow);
            const int  soff = (t * 64 + wave * 16) * 32;
            async_copy16(Ah + arow * K + k0 + schunk, &sA[0][soff]);
            async_copy16(Bh + brow * K + k0 + schunk, &sB[soff]);
            if (SPLIT_A)
                async_copy16(Al + arow * K + k0 + schunk, &sA[NA - 1][soff]);
        }
        __syncthreads();

        bf16x8 aH[4], bH[4];
        #pragma unroll
        for (int i = 0; i < 4; ++i) aH[i] = *(const bf16x8*)&sA[0][(wm + i * 16 + fr) * 32 + fk];
        #pragma unroll
        for (int j = 0; j < 4; ++j) bH[j] = *(const bf16x8*)&sB[(wn + j * 16 + fr) * 32 + fk];

        if (SPLIT_A) {
            bf16x8 aL[4];
            #pragma unroll
            for (int i = 0; i < 4; ++i) aL[i] = *(const bf16x8*)&sA[NA - 1][(wm + i * 16 + fr) * 32 + fk];
            #pragma unroll
            for (int i = 0; i < 4; ++i)
                #pragma unroll
                for (int j = 0; j < 4; ++j) {
                    acc[i][j] = __builtin_amdgcn_mfma_f32_16x16x32_bf16(aH[i], bH[j], acc[i][j], 0, 0, 0);
                    acc[i][j] = __builtin_amdgcn_mfma_f32_16x16x32_bf16(aL[i], bH[j], acc[i][j], 0, 0, 0);
                }
        } else {
            #pragma unroll
            for (int i = 0; i < 4; ++i)
                #pragma unroll
                for (int j = 0; j < 4; ++j)
                    acc[i][j] = __builtin_amdgcn_mfma_f32_16x16x32_bf16(aH[i], bH[j], acc[i][j], 0, 0, 0);
        }
        __syncthreads();
    }

    float* Cf = (float*)Cvoid + (long)bz * sCb;
    __hip_bfloat16* Cb = (__hip_bfloat16*)Cvoid + (long)bz * sCb;
    #pragma unroll
    for (int i = 0; i < 4; ++i) {
        #pragma unroll
        for (int r = 0; r < 4; ++r) {
            const int row = row0 + wm + i * 16 + (lane >> 4) * 4 + r;
            #pragma unroll
            for (int j = 0; j < 4; ++j) {
                const int col = col0 + wn + j * 16 + (lane & 15);
                float val = acc[i][j][r];
                if (HAS_BIAS) val += bias[(long)row * N + col];
                val *= scale;
                if (OUT_BF16)       Cb[(long)row * N + col] = __float2bfloat16(val);
                else if (OUT_TRANS) Cf[(long)col * M + row] = val;
                else                Cf[(long)row * N + col] = val;
            }
        }
    }
}

// fp32 -> bf16, 4 elems/thread
__global__ __launch_bounds__(256)
void convert_bf16_kernel(const float* __restrict__ in, __hip_bfloat16* __restrict__ out, long n)
{
    const long i = ((long)blockIdx.x * 256 + threadIdx.x) * 4;
    if (i >= n) return;
    float va[4];
    *(float4*)va = *(const float4*)(in + i);
    __align__(8) __hip_bfloat16 h[4];
    #pragma unroll
    for (int j = 0; j < 4; ++j) h[j] = __float2bfloat16(va[j]);
    *(uint2*)(out + i) = *(uint2*)h;
}

// fp32 -> (hi, lo) bf16 pair: hi = bf16(x), lo = bf16(x - float(hi))
__global__ __launch_bounds__(256)
void split_convert_kernel(const float* __restrict__ in, __hip_bfloat16* __restrict__ hi,
                          __hip_bfloat16* __restrict__ lo, long n)
{
    const long i = ((long)blockIdx.x * 256 + threadIdx.x) * 4;
    if (i >= n) return;
    float va[4];
    *(float4*)va = *(const float4*)(in + i);
    __align__(8) __hip_bfloat16 h[4], l[4];
    #pragma unroll
    for (int j = 0; j < 4; ++j) {
        h[j] = __float2bfloat16(va[j]);
        l[j] = __float2bfloat16(va[j] - __bfloat162float(h[j]));
    }
    *(uint2*)(hi + i) = *(uint2*)h;
    *(uint2*)(lo + i) = *(uint2*)l;
}

// in [R][C] fp32 -> out [C][R] bf16 (batched via blockIdx.z)
__global__ __launch_bounds__(256)
void transpose_convert_kernel(const float* __restrict__ in, __hip_bfloat16* __restrict__ out,
                              int R, int C, long sIn, long sOut)
{
    in  += (long)blockIdx.z * sIn;
    out += (long)blockIdx.z * sOut;
    __shared__ float t[32][33];
    const int c0 = blockIdx.x * 32, r0 = blockIdx.y * 32;
    for (int i = threadIdx.y; i < 32; i += 8)
        t[i][threadIdx.x] = in[(long)(r0 + i) * C + c0 + threadIdx.x];
    __syncthreads();
    for (int i = threadIdx.y; i < 32; i += 8)
        out[(long)(c0 + i) * R + r0 + threadIdx.x] = __float2bfloat16(t[threadIdx.x][i]);
}

// in-place row softmax over rows of length SEQ; also emits bf16 copy.
__global__ __launch_bounds__(256)
void softmax_kernel(float* __restrict__ data, __hip_bfloat16* __restrict__ data_bf)
{
    const long row = blockIdx.x;
    float* p = data + row * (long)SEQ;
    __hip_bfloat16* pb = data_bf + row * (long)SEQ;
    const int tid = threadIdx.x;
    const int PER = SEQ / 256;  // 8

    float v[PER];
    float m = -1e30f;
    #pragma unroll
    for (int i = 0; i < PER; ++i) {
        v[i] = p[tid + i * 256];
        m = fmaxf(m, v[i]);
    }
    __shared__ float red[256];
    red[tid] = m;
    __syncthreads();
    #pragma unroll
    for (int s = 128; s > 0; s >>= 1) {
        if (tid < s) red[tid] = fmaxf(red[tid], red[tid + s]);
        __syncthreads();
    }
    m = red[0];
    __syncthreads();
    float sum = 0.f;
    #pragma unroll
    for (int i = 0; i < PER; ++i) {
        v[i] = __expf(v[i] - m);
        sum += v[i];
    }
    red[tid] = sum;
    __syncthreads();
    #pragma unroll
    for (int s = 128; s > 0; s >>= 1) {
        if (tid < s) red[tid] += red[tid + s];
        __syncthreads();
    }
    const float inv = 1.0f / red[0];
    #pragma unroll
    for (int i = 0; i < PER; ++i) {
        const float a = v[i] * inv;
        p[tid + i * 256]  = a;
        pb[tid + i * 256] = __float2bfloat16(a);
    }
}

extern "C" void kernel_launch(void* const* d_in, const int* in_sizes, int n_in,
                              void* d_out, int out_size, void* d_ws, size_t ws_size,
                              hipStream_t stream)
{
    const float* q  = (const float*)d_in[0];   // [4, 2048, 1024]
    const float* k  = (const float*)d_in[1];
    const float* v  = (const float*)d_in[2];
    const float* pe = (const float*)d_in[3];   // [10000, 1024], first 2048 rows used
    const float* Uq = (const float*)d_in[4];   // [1024, 1024] (x @ Uq)
    const float* Uk = (const float*)d_in[5];

    float* out      = (float*)d_out;
    float* ctx_out  = out;                                   // [4][1024][2048] (context^T per batch)
    float* attn_out = out + (long)BATCH * SEQ * DMODEL;      // [4][2048][2048]

    const long SD = (long)BATCH * SEQ * DMODEL;   // 8.4M elems
    char* w = (char*)d_ws;
    __hip_bfloat16* q_hi  = (__hip_bfloat16*)w;  w += SD * 2;
    __hip_bfloat16* q_lo  = (__hip_bfloat16*)w;  w += SD * 2;
    __hip_bfloat16* k_bf  = (__hip_bfloat16*)w;  w += SD * 2;
    __hip_bfloat16* pe_bf = (__hip_bfloat16*)w;  w += (long)SEQ * DMODEL * 2;
    __hip_bfloat16* UqT   = (__hip_bfloat16*)w;  w += (long)DMODEL * DMODEL * 2;  // UqT/UkT contiguous
    __hip_bfloat16* UkT   = (__hip_bfloat16*)w;  w += (long)DMODEL * DMODEL * 2;
    __hip_bfloat16* qpe_bf= (__hip_bfloat16*)w;  w += (long)SEQ * DMODEL * 2;     // qpe/kpe contiguous
    __hip_bfloat16* kpe_bf= (__hip_bfloat16*)w;  w += (long)SEQ * DMODEL * 2;
    float*          biasM = (float*)w;           w += (long)SEQ * SEQ * 4;
    // aliases (lifetimes disjoint, stream-ordered):
    __hip_bfloat16* attn_bf = q_hi;   // 33.5M elems needed = q_hi+q_lo region; written by softmax
    __hip_bfloat16* vT      = k_bf;   // 8.4M elems = k_bf region; written after scores GEMM

    const float inv_scale = 1.0f / sqrtf(128.0f);

    // --- conversions
    convert_bf16_kernel<<<dim3((SEQ * DMODEL) / 4 / 256), 256, 0, stream>>>(pe, pe_bf, (long)SEQ * DMODEL);
    transpose_convert_kernel<<<dim3(DMODEL / 32, DMODEL / 32, 1), dim3(32, 8), 0, stream>>>(
        Uq, UqT, DMODEL, DMODEL, 0, 0);
    transpose_convert_kernel<<<dim3(DMODEL / 32, DMODEL / 32, 1), dim3(32, 8), 0, stream>>>(
        Uk, UkT, DMODEL, DMODEL, 0, 0);
    split_convert_kernel<<<dim3(SD / 4 / 256), 256, 0, stream>>>(q, q_hi, q_lo, SD);
    convert_bf16_kernel<<<dim3(SD / 4 / 256), 256, 0, stream>>>(k, k_bf, SD);

    // --- qpe = pe @ Uq, kpe = pe @ Uk  (one batched launch, bf16 out; legacy kernel)
    mfma_gemm<false, false, false, true><<<dim3(DMODEL / 128, SEQ / 128, 2), 256, 0, stream>>>(
        pe_bf, nullptr, UqT, nullptr, qpe_bf, SEQ, DMODEL, DMODEL, 1.0f,
        0, (long)DMODEL * DMODEL, (long)SEQ * DMODEL);

    // --- biasM = qpe @ kpe^T (fp32; legacy kernel)
    mfma_gemm<false, false, false, false><<<dim3(SEQ / 128, SEQ / 128, 1), 256, 0, stream>>>(
        qpe_bf, nullptr, kpe_bf, nullptr, biasM, SEQ, SEQ, DMODEL, 1.0f, 0, 0, 0);

    // --- scores = ((q_hi+q_lo) @ k^T + biasM) * inv_scale
    //     K-concat split: A = [q_hi | q_lo] (K=2048), B = k wrapped (Kb=1024).
    gemm8p<true, 256, true, 2048, 2048, 2048, 1024>
        <<<dim3(SEQ / 256, SEQ / 256, BATCH), 512, 0, stream>>>(
        q_hi, q_lo, k_bf, biasM, attn_out, inv_scale,
        (long)SEQ * DMODEL, (long)SEQ * DMODEL, (long)SEQ * SEQ);

    // --- softmax rows in place + fused bf16 emit
    softmax_kernel<<<dim3(BATCH * SEQ), 256, 0, stream>>>(attn_out, attn_bf);

    // --- v -> v^T bf16
    transpose_convert_kernel<<<dim3(DMODEL / 32, SEQ / 32, BATCH), dim3(32, 8), 0, stream>>>(
        v, vT, SEQ, DMODEL, (long)SEQ * DMODEL, (long)SEQ * DMODEL);

    // --- ctx^T[d][i] = sum_k vT[d][k] * attn[i][k]  (A = vT, B = attn_bf;
    //     row-major coalesced stores into the required [4][1024][2048] layout)
    gemm8p<false, 128, false, 1024, 2048, 2048, 2048>
        <<<dim3(SEQ / 128, DMODEL / 256, BATCH), 512, 0, stream>>>(
        vT, nullptr, attn_bf, nullptr, ctx_out, 1.0f,
        (long)SEQ * DMODEL, (long)SEQ * SEQ, (long)SEQ * DMODEL);
}